// Round 7
// baseline (621.789 us; speedup 1.0000x reference)
//
#include <hip/hip_runtime.h>

static constexpr int KC   = 9;    // kernel bins
static constexpr int CIN  = 32;   // input channels
static constexpr int CA   = 24;   // branch-a out channels
static constexpr int CB   = 8;    // branch-b out channels
static constexpr int COUT = 32;   // CA + CB
static constexpr int WSTR = KC * CIN + 4;   // 292 dwords: W row stride
static constexpr int PPB  = 16;   // output points per block
static constexpr int TPB  = 512;  // threads per block (16 half-waves)
static constexpr int NHW  = TPB / 32;       // 16 half-waves

// ---------------------------------------------------------------------------
// Kernel 1: CSR row pointer from sorted neighbors_out_index.
// ---------------------------------------------------------------------------
__global__ void build_rowptr(const int* __restrict__ oidx, int* __restrict__ rp,
                             int E, int nout) {
    int e = blockIdx.x * blockDim.x + threadIdx.x;
    if (e >= E) return;
    int cur  = oidx[e];
    int prev = (e == 0) ? -1 : oidx[e - 1];
    for (int id = prev + 1; id <= cur; ++id) rp[id] = e;
    if (e == E - 1) {
        for (int id = cur + 1; id <= nout; ++id) rp[id] = E;
    }
}

// ---------------------------------------------------------------------------
// Kernel 2: pack W_a [9][32][24], W_b [9][32][8] into Wt[f][k][c], row
// stride WSTR dwords (f-major), for the per-feature epilogue.
// ---------------------------------------------------------------------------
__global__ void pack_weights(const float* __restrict__ Wa,
                             const float* __restrict__ Wb,
                             float* __restrict__ Wt) {
    int t = blockIdx.x * blockDim.x + threadIdx.x;
    if (t >= COUT * KC * CIN) return;
    int f = t / (KC * CIN);
    int r = t % (KC * CIN);            // k*32 + c
    float v = (f < CA) ? Wa[r * CA + f] : Wb[r * CB + (f - CA)];
    Wt[f * WSTR + r] = v;
}

// ---------------------------------------------------------------------------
// Kernel 3: block-per-16-points fused conv. The block's points own a
// contiguous edge range (noidx sorted); 16 half-waves each process a
// contiguous sub-range, accumulating into per-point LDS S tiles with
// ds_add_f32 (bank == channel == lane: conflict-free). No global atomics,
// no scratch, no cross-block communication. Then the per-feature epilogue
// runs in the same block (2 points per wave).
// ---------------------------------------------------------------------------
__global__ __launch_bounds__(TPB) void fused_block(
    const float* __restrict__ feats, const float* __restrict__ importance,
    const float* __restrict__ Wt, const float* __restrict__ ba,
    const float* __restrict__ bb,
    const int* __restrict__ nidx, const int* __restrict__ nkidx,
    const int* __restrict__ noidx, const int* __restrict__ rp,
    float* __restrict__ outf, float* __restrict__ outimp, int nout)
{
    __shared__ __align__(16) float sW[COUT * WSTR];        // 37376 B
    __shared__ __align__(16) float sS[PPB][2][KC * CIN];   // 36864 B
    __shared__ float sImp[PPB];

    const int tid = threadIdx.x;
    const int hw  = tid >> 5;        // half-wave id 0..15
    const int c   = tid & 31;        // channel lane
    const int p0  = blockIdx.x * PPB;

    // stage weights (coalesced float4) + zero S tiles and importance slots
    {
        const float4* src = reinterpret_cast<const float4*>(Wt);
        float4*       dst = reinterpret_cast<float4*>(sW);
        for (int i = tid; i < COUT * WSTR / 4; i += TPB) dst[i] = src[i];
        float* pS = &sS[0][0][0];
        for (int i = tid; i < PPB * 2 * KC * CIN; i += TPB) pS[i] = 0.f;
        if (tid < PPB) sImp[tid] = 0.f;
    }
    __syncthreads();

    // block's contiguous edge range
    const int pend   = (p0 + PPB < nout) ? (p0 + PPB) : nout;
    const int estart = rp[p0];
    const int eend   = rp[pend];
    const int cnt    = eend - estart;

    // contiguous sub-range per half-wave (uniform within the half-wave)
    const int per = (cnt + NHW - 1) / NHW;
    int a = estart + hw * per;
    int b = a + per; if (b > eend) b = eend;

    float* S0 = &sS[0][0][0];
    int e = a;
    // 4-edge unroll: all loads independent and in flight together
    for (; e + 4 <= b; e += 4) {
        int n0 = noidx[e],     n1 = noidx[e + 1];
        int n2 = noidx[e + 2], n3 = noidx[e + 3];
        int i0 = nidx[e],      i1 = nidx[e + 1];
        int i2 = nidx[e + 2],  i3 = nidx[e + 3];
        int q0 = nkidx[e],     q1 = nkidx[e + 1];
        int q2 = nkidx[e + 2], q3 = nkidx[e + 3];
        float m0 = importance[i0], m1 = importance[i1];
        float m2 = importance[i2], m3 = importance[i3];
        float f0 = feats[(size_t)i0 * CIN + c];
        float f1 = feats[(size_t)i1 * CIN + c];
        float f2 = feats[(size_t)i2 * CIN + c];
        float f3 = feats[(size_t)i3 * CIN + c];
        float* b0 = S0 + (n0 - p0) * (2 * KC * CIN) + q0 * CIN + c;
        float* b1 = S0 + (n1 - p0) * (2 * KC * CIN) + q1 * CIN + c;
        float* b2 = S0 + (n2 - p0) * (2 * KC * CIN) + q2 * CIN + c;
        float* b3 = S0 + (n3 - p0) * (2 * KC * CIN) + q3 * CIN + c;
        atomicAdd(b0, f0);  atomicAdd(b0 + KC * CIN, f0 * m0);
        atomicAdd(b1, f1);  atomicAdd(b1 + KC * CIN, f1 * m1);
        atomicAdd(b2, f2);  atomicAdd(b2 + KC * CIN, f2 * m2);
        atomicAdd(b3, f3);  atomicAdd(b3 + KC * CIN, f3 * m3);
        if (c == 0) {
            atomicAdd(&sImp[n0 - p0], m0);
            atomicAdd(&sImp[n1 - p0], m1);
            atomicAdd(&sImp[n2 - p0], m2);
            atomicAdd(&sImp[n3 - p0], m3);
        }
    }
    for (; e < b; ++e) {
        int   n0 = noidx[e], i0 = nidx[e], q0 = nkidx[e];
        float m0 = importance[i0];
        float f0 = feats[(size_t)i0 * CIN + c];
        float* bp = S0 + (n0 - p0) * (2 * KC * CIN) + q0 * CIN + c;
        atomicAdd(bp, f0);
        atomicAdd(bp + KC * CIN, f0 * m0);
        if (c == 0) atomicAdd(&sImp[n0 - p0], m0);
    }
    __syncthreads();

    // ---- epilogue: 8 waves x 2 points each, per-feature dot product ----
    const int wave = tid >> 6;       // 0..7
    const int lane = tid & 63;
    const int f    = lane & 31;
    const int h    = lane >> 5;
#pragma unroll
    for (int rep = 0; rep < 2; ++rep) {
        const int slot = wave * 2 + rep;
        const int n    = p0 + slot;
        if (n >= nout) break;        // uniform per wave

        float impTot = sImp[slot];
        float denom  = impTot > 0.f ? impTot : 1.f;

        const float* Sbase = &sS[slot][(f < CA) ? 0 : 1][0];
        const float* Wbase = sW + f * WSTR;
        float acc0 = 0.f, acc1 = 0.f, acc2 = 0.f, acc3 = 0.f;
#pragma unroll
        for (int k = 0; k < KC; ++k) {
            int off = k * CIN + h * 16;
            float4 s0 = *reinterpret_cast<const float4*>(Sbase + off);
            float4 s1 = *reinterpret_cast<const float4*>(Sbase + off + 4);
            float4 s2 = *reinterpret_cast<const float4*>(Sbase + off + 8);
            float4 s3 = *reinterpret_cast<const float4*>(Sbase + off + 12);
            float4 w0 = *reinterpret_cast<const float4*>(Wbase + off);
            float4 w1 = *reinterpret_cast<const float4*>(Wbase + off + 4);
            float4 w2 = *reinterpret_cast<const float4*>(Wbase + off + 8);
            float4 w3 = *reinterpret_cast<const float4*>(Wbase + off + 12);
            acc0 = fmaf(s0.x, w0.x, fmaf(s0.y, w0.y, fmaf(s0.z, w0.z, fmaf(s0.w, w0.w, acc0))));
            acc1 = fmaf(s1.x, w1.x, fmaf(s1.y, w1.y, fmaf(s1.z, w1.z, fmaf(s1.w, w1.w, acc1))));
            acc2 = fmaf(s2.x, w2.x, fmaf(s2.y, w2.y, fmaf(s2.z, w2.z, fmaf(s2.w, w2.w, acc2))));
            acc3 = fmaf(s3.x, w3.x, fmaf(s3.y, w3.y, fmaf(s3.z, w3.z, fmaf(s3.w, w3.w, acc3))));
        }
        float acc = (acc0 + acc1) + (acc2 + acc3);
        float tot = acc + __shfl_xor(acc, 32, 64);   // combine channel halves

        if (h == 0) {
            float res = (f < CA) ? (tot + ba[f]) : (tot / denom + bb[f - CA]);
            outf[(size_t)n * COUT + f] = fmaxf(res, 0.f);
        }
        if (lane == 0) outimp[n] = impTot;
    }
}

// ---------------------------------------------------------------------------
extern "C" void kernel_launch(void* const* d_in, const int* in_sizes, int n_in,
                              void* d_out, int out_size, void* d_ws, size_t ws_size,
                              hipStream_t stream) {
    const float* feats      = (const float*)d_in[0];
    const float* importance = (const float*)d_in[1];
    const float* Wa         = (const float*)d_in[2];
    const float* ba         = (const float*)d_in[3];
    const float* Wb         = (const float*)d_in[4];
    const float* bb         = (const float*)d_in[5];
    const int*   nidx       = (const int*)d_in[6];
    const int*   nkidx      = (const int*)d_in[7];
    const int*   noidx      = (const int*)d_in[8];

    const int E    = in_sizes[6];
    const int nout = out_size / (COUT + 1);

    float* outf   = (float*)d_out;
    float* outimp = outf + (size_t)nout * COUT;

    // workspace: row_ptr [(nout+1) ints] | Wt [COUT*WSTR floats]
    int*   rp = (int*)d_ws;
    size_t rp_bytes = ((size_t)(nout + 1) * sizeof(int) + 255) & ~(size_t)255;
    float* Wt = (float*)((char*)d_ws + rp_bytes);

    build_rowptr<<<(E + 255) / 256, 256, 0, stream>>>(noidx, rp, E, nout);
    pack_weights<<<(COUT * KC * CIN + 255) / 256, 256, 0, stream>>>(Wa, Wb, Wt);
    fused_block<<<(nout + PPB - 1) / PPB, TPB, 0, stream>>>(
        feats, importance, Wt, ba, bb, nidx, nkidx, noidx, rp,
        outf, outimp, nout);
}